// Round 6
// baseline (236.267 us; speedup 1.0000x reference)
//
#include <hip/hip_runtime.h>
#include <hip/hip_fp16.h>

#define N_NODES 100000
#define N_EDGES 1600000
#define N_GRAPHS 512
#define FEAT 128
#define EMB 32
#define ZROW N_NODES                        // dedicated zero row in hs table
#define NCOPY 64                            // privatized pool accumulator copies
#define NBKT 500                            // dst buckets
#define NPB 200                             // nodes per bucket
#define CAPB 4096                           // binbuf slots per bucket (avg 3200, 16-sigma safe)
#define COLCAP 5120                         // col slots per bucket (cnt + 7*NPB pad max ~4900)
#define ABLK 512                            // scatter blocks
#define EPB 3125                            // edges per scatter block
#define NTILE (N_NODES / 16)                // 6250 MFMA row tiles
#define AGB 1563                            // agg blocks (64 nodes/block: 4 waves x 16 nodes)

typedef unsigned short u16;
typedef unsigned int u32;
typedef _Float16 f16;
typedef float f32x4 __attribute__((ext_vector_type(4)));
typedef unsigned short u16x4 __attribute__((ext_vector_type(4)));
typedef unsigned short u16x8 __attribute__((ext_vector_type(8)));
typedef f16 f16x8 __attribute__((ext_vector_type(8)));

__device__ __forceinline__ float4 h4_to_f4(u16x4 v) {
  union { unsigned int u; __half2 h; } a, b;
  a.u = (unsigned int)v.x | ((unsigned int)v.y << 16);
  b.u = (unsigned int)v.z | ((unsigned int)v.w << 16);
  float2 f0 = __half22float2(a.h);
  float2 f1 = __half22float2(b.h);
  return make_float4(f0.x, f0.y, f1.x, f1.y);
}

__device__ __forceinline__ u16x4 f4_to_h4(float4 f) {
  union { unsigned int u; __half2 h; } a, b;
  a.h = __float22half2_rn(make_float2(f.x, f.y));
  b.h = __float22half2_rn(make_float2(f.z, f.w));
  u16x4 r;
  r.x = (u16)(a.u & 0xffff); r.y = (u16)(a.u >> 16);
  r.z = (u16)(b.u & 0xffff); r.w = (u16)(b.u >> 16);
  return r;
}

__device__ __forceinline__ float4 relu_row(float4 acc, float d, float4 bq) {
  float4 o;
  o.x = fmaxf(fmaf(acc.x, d, bq.x), 0.f);
  o.y = fmaxf(fmaf(acc.y, d, bq.y), 0.f);
  o.z = fmaxf(fmaf(acc.z, d, bq.z), 0.f);
  o.w = fmaxf(fmaf(acc.w, d, bq.w), 0.f);
  return o;
}

// ---------------- k_scat: histogram + atomic block-reservation + scatter ----------------

__global__ __launch_bounds__(256) void k_scat(const int* __restrict__ src,
                                              const int* __restrict__ dst,
                                              int* __restrict__ cur,
                                              u32* __restrict__ binbuf) {
  __shared__ int h[NBKT];
  __shared__ int posB[NBKT];
  int k = blockIdx.x, t = threadIdx.x;
  for (int i = t; i < NBKT; i += 256) h[i] = 0;
  __syncthreads();
  int e0 = k * EPB;
  int e1 = min(e0 + EPB, N_EDGES);
  for (int e = e0 + t; e < e1; e += 256)
    atomicAdd(&h[(u32)dst[e] / (u32)NPB], 1);
  __syncthreads();
  for (int i = t; i < NBKT; i += 256) {
    int c = h[i];
    posB[i] = c ? atomicAdd(&cur[i], c) : 0;
    h[i] = 0;                               // reuse as local cursor
  }
  __syncthreads();
  for (int e = e0 + t; e < e1; e += 256) {
    u32 d = (u32)dst[e];
    int b = d / (u32)NPB;
    int r = atomicAdd(&h[b], 1);
    binbuf[(size_t)b * CAPB + posB[b] + r] = (u32)src[e] * (u32)NPB + (d - (u32)b * NPB);
  }
}

// ---------------- k_build: per-bucket CSR (hist + LDS scan + scatter + pad) ----------------

__global__ __launch_bounds__(256) void k_build(const u32* __restrict__ binbuf,
                                               const int* __restrict__ cur,
                                               int* __restrict__ col,
                                               int2* __restrict__ rowinfo,
                                               float* __restrict__ dis,
                                               u16* __restrict__ hs1) {
  __shared__ int c[NPB];     // histogram, then scatter cursor
  __shared__ int sc[256];    // scan workspace
  __shared__ int rpl[NPB];   // exclusive scan of pad8(deg)
  int b = blockIdx.x, t = threadIdx.x;
  int cnt = cur[b];
  const u32* eb = binbuf + (size_t)b * CAPB;
  for (int i = t; i < NPB; i += 256) c[i] = 0;
  __syncthreads();
  for (int i = t; i < cnt; i += 256) {
    u32 p = eb[i];
    u32 s = p / (u32)NPB;
    atomicAdd(&c[p - s * (u32)NPB], 1);
  }
  __syncthreads();
  int deg = (t < NPB) ? c[t] : 0;
  int p8 = (deg + 7) & ~7;
  sc[t] = p8;
  __syncthreads();
  for (int o = 1; o < 256; o <<= 1) {
    int add = (t >= o) ? sc[t - o] : 0;
    __syncthreads();
    sc[t] += add;
    __syncthreads();
  }
  int colbase = b * COLCAP;
  if (t < NPB) {
    int rp = sc[t] - p8;
    rpl[t] = rp;
    int node = b * NPB + t;
    rowinfo[node] = make_int2(colbase + rp, p8);
    dis[node] = rsqrtf((float)deg + 1.0f);
    for (int j = deg; j < p8; j++) col[colbase + rp + j] = ZROW;  // pad slots
    c[t] = 0;                                                     // reset as cursor
  }
  __syncthreads();
  for (int i = t; i < cnt; i += 256) {
    u32 p = eb[i];
    u32 s = p / (u32)NPB;
    int ld = (int)(p - s * (u32)NPB);
    int pos = atomicAdd(&c[ld], 1);
    col[colbase + rpl[ld] + pos] = (int)s;
  }
  if (b == 0)
    for (int i = t; i < EMB; i += 256) hs1[(size_t)ZROW * EMB + i] = 0;
}

// ---------------- GEMMs via MFMA 16x16x32 f16 (W in register B-frags) ----------------

__global__ __launch_bounds__(256) void k_gemm1(const float* __restrict__ x,
                                               const float* __restrict__ W1,
                                               const float* __restrict__ dis,
                                               u16* __restrict__ hs1) {
  int wid = (blockIdx.x * 256 + threadIdx.x) >> 6;   // wave id = 16-row tile
  if (wid >= NTILE) return;
  int l = threadIdx.x & 63;
  int m = l & 15, q = l >> 4;
  f16x8 B[4][2];
#pragma unroll
  for (int s = 0; s < 4; ++s)
#pragma unroll
    for (int h = 0; h < 2; ++h)
#pragma unroll
      for (int j = 0; j < 8; ++j)
        B[s][h][j] = (f16)W1[(s * 32 + q * 8 + j) * EMB + h * 16 + m];
  int row = wid * 16 + m;
  const float* xr = x + (size_t)row * FEAT + q * 8;
  f32x4 acc0 = {0.f, 0.f, 0.f, 0.f}, acc1 = {0.f, 0.f, 0.f, 0.f};
#pragma unroll
  for (int s = 0; s < 4; ++s) {
    f32x4 xa = __builtin_nontemporal_load((const f32x4*)(xr + s * 32));
    f32x4 xb = __builtin_nontemporal_load((const f32x4*)(xr + s * 32 + 4));
    f16x8 A;
    A[0] = (f16)xa.x; A[1] = (f16)xa.y; A[2] = (f16)xa.z; A[3] = (f16)xa.w;
    A[4] = (f16)xb.x; A[5] = (f16)xb.y; A[6] = (f16)xb.z; A[7] = (f16)xb.w;
    acc0 = __builtin_amdgcn_mfma_f32_16x16x32_f16(A, B[s][0], acc0, 0, 0, 0);
    acc1 = __builtin_amdgcn_mfma_f32_16x16x32_f16(A, B[s][1], acc1, 0, 0, 0);
  }
  f32x4 dq = *(const f32x4*)(dis + wid * 16 + q * 4);
  u16* o = hs1 + (size_t)(wid * 16) * EMB;
#pragma unroll
  for (int i = 0; i < 4; ++i) {
    int r = q * 4 + i;
    float dv = (i == 0) ? dq.x : (i == 1) ? dq.y : (i == 2) ? dq.z : dq.w;
    o[(size_t)r * EMB + m]      = __half_as_ushort(__float2half_rn(acc0[i] * dv));
    o[(size_t)r * EMB + 16 + m] = __half_as_ushort(__float2half_rn(acc1[i] * dv));
  }
}

__global__ __launch_bounds__(256) void k_gemm2(const u16* __restrict__ in1,
                                               const float* __restrict__ W2,
                                               const float* __restrict__ dis,
                                               u16* __restrict__ hs2) {
  int wid = (blockIdx.x * 256 + threadIdx.x) >> 6;
  if (wid >= NTILE) return;
  int l = threadIdx.x & 63;
  int m = l & 15, q = l >> 4;
  f16x8 B[2];
#pragma unroll
  for (int h = 0; h < 2; ++h)
#pragma unroll
    for (int j = 0; j < 8; ++j)
      B[h][j] = (f16)W2[(q * 8 + j) * EMB + h * 16 + m];
  int row = wid * 16 + m;
  f16x8 A = *(const f16x8*)(in1 + (size_t)row * EMB + q * 8);
  f32x4 acc0 = {0.f, 0.f, 0.f, 0.f}, acc1 = {0.f, 0.f, 0.f, 0.f};
  acc0 = __builtin_amdgcn_mfma_f32_16x16x32_f16(A, B[0], acc0, 0, 0, 0);
  acc1 = __builtin_amdgcn_mfma_f32_16x16x32_f16(A, B[1], acc1, 0, 0, 0);
  f32x4 dq = *(const f32x4*)(dis + wid * 16 + q * 4);
  u16* o = hs2 + (size_t)(wid * 16) * EMB;
#pragma unroll
  for (int i = 0; i < 4; ++i) {
    int r = q * 4 + i;
    float dv = (i == 0) ? dq.x : (i == 1) ? dq.y : (i == 2) ? dq.z : dq.w;
    o[(size_t)r * EMB + m]      = __half_as_ushort(__float2half_rn(acc0[i] * dv));
    o[(size_t)r * EMB + 16 + m] = __half_as_ushort(__float2half_rn(acc1[i] * dv));
  }
}

// ---------------- Aggregation: 4 lanes/node, 16B chunks, A/B pipelined ----------------
// R6 experiment (only change vs R5): per-edge vmem instruction count halved
// (4 lanes x 16B cover the 64B row; one wave-load = 16 rows) and the next 8-slot
// gather set issues BEFORE the current set is consumed (A/B register pipeline ->
// s_waitcnt leaves 8 loads in flight instead of draining). Theory: aggs are
// vmem-instruction/stall bound (R1 PMC: VALU 50%, occ 70%, HBM 13%), not line-bound.

__device__ __forceinline__ void acc8(float4& L, float4& H, u16x8 v) {
  union { u16x8 v8; __half2 h2[4]; } u;
  u.v8 = v;
  float2 f0 = __half22float2(u.h2[0]);
  float2 f1 = __half22float2(u.h2[1]);
  float2 f2 = __half22float2(u.h2[2]);
  float2 f3 = __half22float2(u.h2[3]);
  L.x += f0.x; L.y += f0.y; L.z += f1.x; L.w += f1.y;
  H.x += f2.x; H.y += f2.y; H.z += f3.x; H.w += f3.y;
}

__device__ __forceinline__ void agg_node16(const u16* __restrict__ hs,
                                           const int2* __restrict__ rowinfo,
                                           const int* __restrict__ col,
                                           int node, int sub,
                                           float4& L, float4& H) {
  const u16x8* t8 = (const u16x8*)hs;          // row = 4 chunks of 16B
  int2 ri = rowinfo[node];
  int a0 = ri.x, na = ri.y;                    // pad8 degree; a0 8-slot aligned
  const int* cp = col + a0;
  L = make_float4(0.f, 0.f, 0.f, 0.f);
  H = make_float4(0.f, 0.f, 0.f, 0.f);
  if (na > 0) {
    int4 c0 = *(const int4*)cp;
    int4 c1 = *(const int4*)(cp + 4);
    u16x8 A0 = t8[(size_t)c0.x * 4 + sub];
    u16x8 A1 = t8[(size_t)c0.y * 4 + sub];
    u16x8 A2 = t8[(size_t)c0.z * 4 + sub];
    u16x8 A3 = t8[(size_t)c0.w * 4 + sub];
    u16x8 A4 = t8[(size_t)c1.x * 4 + sub];
    u16x8 A5 = t8[(size_t)c1.y * 4 + sub];
    u16x8 A6 = t8[(size_t)c1.z * 4 + sub];
    u16x8 A7 = t8[(size_t)c1.w * 4 + sub];
    for (int i = 8; i < na; i += 8) {
      int4 d0 = *(const int4*)(cp + i);
      int4 d1 = *(const int4*)(cp + i + 4);
      u16x8 B0 = t8[(size_t)d0.x * 4 + sub];   // issue next set before consuming A
      u16x8 B1 = t8[(size_t)d0.y * 4 + sub];
      u16x8 B2 = t8[(size_t)d0.z * 4 + sub];
      u16x8 B3 = t8[(size_t)d0.w * 4 + sub];
      u16x8 B4 = t8[(size_t)d1.x * 4 + sub];
      u16x8 B5 = t8[(size_t)d1.y * 4 + sub];
      u16x8 B6 = t8[(size_t)d1.z * 4 + sub];
      u16x8 B7 = t8[(size_t)d1.w * 4 + sub];
      acc8(L, H, A0); acc8(L, H, A1); acc8(L, H, A2); acc8(L, H, A3);
      acc8(L, H, A4); acc8(L, H, A5); acc8(L, H, A6); acc8(L, H, A7);
      A0 = B0; A1 = B1; A2 = B2; A3 = B3;
      A4 = B4; A5 = B5; A6 = B6; A7 = B7;
    }
    acc8(L, H, A0); acc8(L, H, A1); acc8(L, H, A2); acc8(L, H, A3);
    acc8(L, H, A4); acc8(L, H, A5); acc8(L, H, A6); acc8(L, H, A7);
  }
  // self-loop contribution (row pre-scaled by dis[node] at GEMM time)
  acc8(L, H, t8[(size_t)node * 4 + sub]);
}

// grid = 1563 blocks; wave handles 16 nodes, lane group (l>>2) one node, sub=l&3
__global__ __launch_bounds__(256) void k_agg1(const u16* __restrict__ hs,
                                              const int2* __restrict__ rowinfo,
                                              const int* __restrict__ col,
                                              const float* __restrict__ dis,
                                              const float* __restrict__ b,
                                              u16* __restrict__ out) {
  int t = threadIdx.x;
  int l = t & 63;
  int wbase = blockIdx.x * 64 + (t >> 6) * 16;
  if (wbase >= N_NODES) return;                // wave-uniform tail guard
  int node = wbase + (l >> 2);
  int sub = l & 3;
  float4 L, H;
  agg_node16(hs, rowinfo, col, node, sub, L, H);
  float d = dis[node];
  float4 bL = ((const float4*)b)[sub * 2];
  float4 bH = ((const float4*)b)[sub * 2 + 1];
  float4 oL = relu_row(L, d, bL);
  float4 oH = relu_row(H, d, bH);
  u16x4 lo = f4_to_h4(oL), hi = f4_to_h4(oH);
  u16x8 r;
  r[0] = lo.x; r[1] = lo.y; r[2] = lo.z; r[3] = lo.w;
  r[4] = hi.x; r[5] = hi.y; r[6] = hi.z; r[7] = hi.w;
  *(u16x8*)(out + (size_t)node * EMB + sub * 8) = r;
}

__global__ __launch_bounds__(256) void k_agg2pool(const u16* __restrict__ hs,
                                                  const int2* __restrict__ rowinfo,
                                                  const int* __restrict__ col,
                                                  const float* __restrict__ dis,
                                                  const float* __restrict__ b2,
                                                  const float* __restrict__ Wo,
                                                  const int* __restrict__ batch,
                                                  float* __restrict__ gaccP) {
  int t = threadIdx.x;
  int l = t & 63;
  int wbase = blockIdx.x * 64 + (t >> 6) * 16;
  if (wbase >= N_NODES) return;
  int node = wbase + (l >> 2);
  int sub = l & 3;
  float4 L, H;
  agg_node16(hs, rowinfo, col, node, sub, L, H);
  float d = dis[node];
  float4 bL = ((const float4*)b2)[sub * 2];
  float4 bH = ((const float4*)b2)[sub * 2 + 1];
  float4 wL = ((const float4*)Wo)[sub * 2];
  float4 wH = ((const float4*)Wo)[sub * 2 + 1];
  float4 oL = relu_row(L, d, bL);
  float4 oH = relu_row(H, d, bH);
  float p = oL.x * wL.x + oL.y * wL.y + oL.z * wL.z + oL.w * wL.w
          + oH.x * wH.x + oH.y * wH.y + oH.z * wH.z + oH.w * wH.w;
  p += __shfl_xor(p, 1);
  p += __shfl_xor(p, 2);
  if (sub == 0)
    atomicAdd(&gaccP[(node & (NCOPY - 1)) * N_GRAPHS + batch[node]], p);
}

// finalize (absorbs k_gcnt: per-graph node count via binary search on sorted batch)
__global__ __launch_bounds__(256) void k_finalize(const float* __restrict__ gaccP,
                                                  const int* __restrict__ batch,
                                                  const float* __restrict__ bo,
                                                  float* __restrict__ out) {
  int g = blockIdx.x * 256 + threadIdx.x;
  if (g < N_GRAPHS) {
    int lo = 0, hi = N_NODES;
    while (lo < hi) { int mid = (lo + hi) >> 1; if (batch[mid] < g) lo = mid + 1; else hi = mid; }
    int lo1 = lo; hi = N_NODES;
    while (lo < hi) { int mid = (lo + hi) >> 1; if (batch[mid] < g + 1) lo = mid + 1; else hi = mid; }
    int cntg = lo - lo1;
    float s = 0.f;
#pragma unroll 8
    for (int c = 0; c < NCOPY; ++c) s += gaccP[c * N_GRAPHS + g];
    out[g] = s / fmaxf((float)cntg, 1.0f) + bo[0];
  }
}

// ---------------- launch ----------------

extern "C" void kernel_launch(void* const* d_in, const int* in_sizes, int n_in,
                              void* d_out, int out_size, void* d_ws, size_t ws_size,
                              hipStream_t stream) {
  const float* x     = (const float*)d_in[0];
  const int*   ei    = (const int*)d_in[1];   // [2, E]: src then dst
  const int*   batch = (const int*)d_in[2];
  const float* W1    = (const float*)d_in[3];
  const float* b1    = (const float*)d_in[4];
  const float* W2    = (const float*)d_in[5];
  const float* b2    = (const float*)d_in[6];
  const float* Wo    = (const float*)d_in[7];
  const float* bo    = (const float*)d_in[8];
  float* out = (float*)d_out;

  const int* src = ei;
  const int* dst = ei + N_EDGES;

  char* w = (char*)d_ws;
  float* gaccP   = (float*)w;  w += (size_t)NCOPY * N_GRAPHS * 4;     // zeroed
  int*   cur     = (int*)w;    w += (size_t)(NBKT + 8) * 4;           // zeroed
  size_t zero_bytes = (size_t)(w - (char*)d_ws);
  u32*   binbuf  = (u32*)w;    w += (size_t)NBKT * CAPB * 4;          // 8.2 MB
  int*   col     = (int*)w;    w += ((size_t)NBKT * COLCAP + 64) * 4; // 10.2 MB
  int2*  rowinfo = (int2*)w;   w += (size_t)(N_NODES + 8) * 8;        // 800 KB
  float* dis     = (float*)w;  w += (size_t)N_NODES * 4;
  u16*   hs1     = (u16*)w;    w += (size_t)(N_NODES + 1) * EMB * 2;  // +1 zero row
  u16*   out1    = (u16*)w;    w += (size_t)N_NODES * EMB * 2;        // 6.4 MB
  u16*   hs2     = hs1;        // hs1 dead after agg1; zero row persists

  const int GB = (NTILE * 64 + 255) / 256;  // 1563 MFMA blocks

  (void)hipMemsetAsync(d_ws, 0, zero_bytes, stream);

  k_scat<<<ABLK, 256, 0, stream>>>(src, dst, cur, binbuf);
  k_build<<<NBKT, 256, 0, stream>>>(binbuf, cur, col, rowinfo, dis, hs1);
  k_gemm1<<<GB, 256, 0, stream>>>(x, W1, dis, hs1);
  k_agg1<<<AGB, 256, 0, stream>>>(hs1, rowinfo, col, dis, b1, out1);
  k_gemm2<<<GB, 256, 0, stream>>>(out1, W2, dis, hs2);
  k_agg2pool<<<AGB, 256, 0, stream>>>(hs2, rowinfo, col, dis, b2, Wo, batch, gaccP);
  k_finalize<<<2, 256, 0, stream>>>(gaccP, batch, bo, out);
}